// Round 1
// baseline (593.151 us; speedup 1.0000x reference)
//
#include <hip/hip_runtime.h>
#include <hip/hip_bf16.h>

#define HW 65536
#define CCH 128

// ---------------- K1: adaptive avg pool 256x256 -> 8x8 (block means) ----------------
__global__ __launch_bounds__(256) void pool_kernel(const float* __restrict__ x,
                                                   float* __restrict__ pooled) {
    int bc = blockIdx.x;                 // b*C + c, 0..1023
    const float* base = x + (size_t)bc * HW;
    int t = threadIdx.x;                 // column 0..255
    for (int py = 0; py < 8; ++py) {
        float acc = 0.f;
        const float* rowp = base + py * 32 * 256 + t;
        #pragma unroll
        for (int r = 0; r < 32; ++r) acc += rowp[r * 256];
        // reduce 32 columns per pooled cell (groups of 32 lanes)
        for (int off = 16; off > 0; off >>= 1) acc += __shfl_down(acc, off, 32);
        if ((t & 31) == 0)
            pooled[(size_t)bc * 64 + py * 8 + (t >> 5)] = acc * (1.0f / 1024.0f);
    }
}

// ---------------- K2: q = relu(pooled@Wq^T+bq), k likewise ----------------
__global__ __launch_bounds__(256) void qk_kernel(const float* __restrict__ pooled,
        const float* __restrict__ Wq, const float* __restrict__ bq,
        const float* __restrict__ Wk, const float* __restrict__ bk,
        float* __restrict__ qo, float* __restrict__ ko) {
    int bc = blockIdx.x;
    int t = threadIdx.x;
    __shared__ float ps[64];
    if (t < 64) ps[t] = pooled[(size_t)bc * 64 + t];
    __syncthreads();
    for (int m = 0; m < 2; ++m) {
        const float* W = m ? Wk : Wq;
        const float* bb = m ? bk : bq;
        float* o = m ? ko : qo;
        for (int oi = t; oi < 512; oi += 256) {
            float acc = bb[oi];
            const float* wr = W + oi * 64;
            #pragma unroll
            for (int p = 0; p < 64; ++p) acc += ps[p] * wr[p];
            o[(size_t)bc * 512 + oi] = fmaxf(acc, 0.f);
        }
    }
}

// ---------------- K3: per (b,h): A=q@k^T, rownorm, M=A_n@Wv, beta=A_n@bv ----------------
__global__ __launch_bounds__(256) void am_kernel(const float* __restrict__ q,
        const float* __restrict__ k,
        const float* __restrict__ Wv, const float* __restrict__ bv,
        float* __restrict__ M, float* __restrict__ beta) {
    int bh = blockIdx.x;                 // b*8 + h
    int b = bh >> 3, h = bh & 7;
    int t = threadIdx.x;
    __shared__ float smem[128 * 128];    // 64 KB: first qs[128][64]+ks[128][64], later As[128][128]
    float* qs = smem;                    // [c][p]
    float* ks = smem + 128 * 64;         // [d][p]
    for (int i = t; i < 128 * 64; i += 256) {
        int c = i >> 6, p = i & 63;
        qs[c * 64 + p] = q[((size_t)(b * CCH + c)) * 512 + h * 64 + p];
        ks[c * 64 + p] = k[((size_t)(b * CCH + c)) * 512 + h * 64 + p];
    }
    __syncthreads();
    int c = t >> 1, half = t & 1;
    float a[64];
    for (int j = 0; j < 64; ++j) {
        int d = half * 64 + j;
        float acc = 0.f;
        #pragma unroll
        for (int p = 0; p < 64; ++p) acc += qs[c * 64 + p] * ks[d * 64 + p];
        a[j] = acc;
    }
    float s = 0.f;
    for (int j = 0; j < 64; ++j) s += a[j];
    s += __shfl_xor(s, 1);               // combine the two halves (adjacent lanes)
    float inv = 1.0f / (s + 1e-7f);
    __syncthreads();                     // done reading qs/ks; reuse smem as As
    float* As = smem;                    // [c][d] 128x128
    for (int j = 0; j < 64; ++j) As[c * 128 + half * 64 + j] = a[j] * inv;
    __syncthreads();
    // M[c][e] = sum_d As[c][d] * Wv[d][e]
    float acc2[64];
    for (int j = 0; j < 64; ++j) acc2[j] = 0.f;
    for (int d = 0; d < 128; ++d) {
        float av = As[c * 128 + d];
        const float* wr = Wv + d * 128 + half * 64;
        #pragma unroll
        for (int j = 0; j < 64; ++j) acc2[j] += av * wr[j];
    }
    for (int j = 0; j < 64; ++j)
        M[((size_t)bh * 128 + c) * 128 + half * 64 + j] = acc2[j];
    if (half == 0) {
        float bacc = 0.f;
        for (int d = 0; d < 128; ++d) bacc += As[c * 128 + d] * bv[d];
        beta[bh * 128 + c] = bacc;
    }
}

// ---------------- K4: attn[b,c,s] = sum_e M[b,h,c,e]*x[b,e,s] + beta[b,h,c] (bf16 out) ----------------
__global__ __launch_bounds__(256) void attn_kernel(const float* __restrict__ x,
        const float* __restrict__ M, const float* __restrict__ beta,
        __hip_bfloat16* __restrict__ attn) {
    int bid = blockIdx.x;                // b*512 + h*64 + tile
    int b = bid >> 9;
    int h = (bid >> 6) & 7;
    int tile = bid & 63;
    int s0 = h * 8192 + tile * 128;
    int t = threadIdx.x;
    int tr = t >> 4;                     // 0..15 channel group
    int tc = t & 15;                     // 0..15 spatial group
    __shared__ __align__(16) float xs[16][128];
    __shared__ __align__(16) float Ms[16][136];   // Ms[ee][c]
    const float* Mbase = M + (size_t)(b * 8 + h) * 128 * 128;
    float acc[8][8] = {};
    for (int e0 = 0; e0 < 128; e0 += 16) {
        // stage x tile: 16 e-rows x 128 spatial
        {
            int er = t >> 5;             // 0..7
            int c4 = (t & 31) * 4;       // 0..124
            const float* xp = x + ((size_t)(b * CCH + e0 + er)) * HW + s0 + c4;
            *(float4*)&xs[er][c4] = *(const float4*)xp;
            const float* xp2 = x + ((size_t)(b * CCH + e0 + er + 8)) * HW + s0 + c4;
            *(float4*)&xs[er + 8][c4] = *(const float4*)xp2;
        }
        // stage M tile transposed: Ms[ee][c]
        {
            int c = t >> 1;
            int eh = (t & 1) * 8;
            float4 v0 = *(const float4*)&Mbase[c * 128 + e0 + eh];
            float4 v1 = *(const float4*)&Mbase[c * 128 + e0 + eh + 4];
            Ms[eh + 0][c] = v0.x; Ms[eh + 1][c] = v0.y;
            Ms[eh + 2][c] = v0.z; Ms[eh + 3][c] = v0.w;
            Ms[eh + 4][c] = v1.x; Ms[eh + 5][c] = v1.y;
            Ms[eh + 6][c] = v1.z; Ms[eh + 7][c] = v1.w;
        }
        __syncthreads();
        #pragma unroll
        for (int ee = 0; ee < 16; ++ee) {
            float4 ma = *(const float4*)&Ms[ee][tr * 8];
            float4 mb = *(const float4*)&Ms[ee][tr * 8 + 4];
            float4 xa = *(const float4*)&xs[ee][tc * 8];
            float4 xb = *(const float4*)&xs[ee][tc * 8 + 4];
            float mv[8] = {ma.x, ma.y, ma.z, ma.w, mb.x, mb.y, mb.z, mb.w};
            float xv[8] = {xa.x, xa.y, xa.z, xa.w, xb.x, xb.y, xb.z, xb.w};
            #pragma unroll
            for (int i = 0; i < 8; ++i)
                #pragma unroll
                for (int j = 0; j < 8; ++j)
                    acc[i][j] += mv[i] * xv[j];
        }
        __syncthreads();
    }
    const float* bet = beta + (b * 8 + h) * 128;
    for (int i = 0; i < 8; ++i) {
        int c = tr * 8 + i;
        float bb = bet[c];
        __hip_bfloat16* op = attn + ((size_t)(b * CCH + c)) * HW + s0 + tc * 8;
        union { ushort4 v; __hip_bfloat16 hh[4]; } p0, p1;
        #pragma unroll
        for (int j = 0; j < 4; ++j) p0.hh[j] = __float2bfloat16(acc[i][j] + bb);
        #pragma unroll
        for (int j = 0; j < 4; ++j) p1.hh[j] = __float2bfloat16(acc[i][4 + j] + bb);
        *(ushort4*)op = p0.v;
        *(ushort4*)(op + 4) = p1.v;
    }
}

// ---------------- K5: depthwise 3x3 pad1 + bp, bf16 in -> fp32 out ----------------
__global__ __launch_bounds__(256) void dwconv_kernel(const __hip_bfloat16* __restrict__ attn,
        const float* __restrict__ Wp, const float* __restrict__ bp,
        float* __restrict__ out) {
    int bid = blockIdx.x;                // bc*16 + ty*4 + tx
    int bc = bid >> 4;
    int ty = (bid >> 2) & 3, tx = bid & 3;
    int y0 = ty * 64, x0 = tx * 64;
    int t = threadIdx.x;
    __shared__ __hip_bfloat16 tile[66][72];
    const __hip_bfloat16* base = attn + (size_t)bc * HW;
    for (int i = t; i < 66 * 66; i += 256) {
        int r = i / 66, cc = i % 66;
        int gy = y0 + r - 1, gx = x0 + cc - 1;
        float v = 0.f;
        if (gy >= 0 && gy < 256 && gx >= 0 && gx < 256)
            v = __bfloat162float(base[gy * 256 + gx]);
        tile[r][cc] = __float2bfloat16(v);
    }
    __syncthreads();
    int c = bc & 127;
    float w[9];
    #pragma unroll
    for (int j = 0; j < 9; ++j) w[j] = Wp[c * 9 + j];
    float bias = bp[c];
    float* obase = out + (size_t)bc * HW;
    for (int i = t; i < 4096; i += 256) {
        int r = i >> 6, cc = i & 63;
        float acc = bias;
        #pragma unroll
        for (int dy = 0; dy < 3; ++dy)
            #pragma unroll
            for (int dx = 0; dx < 3; ++dx)
                acc += w[dy * 3 + dx] * __bfloat162float(tile[r + dy][cc + dx]);
        obase[(size_t)(y0 + r) * 256 + x0 + cc] = acc;
    }
}

extern "C" void kernel_launch(void* const* d_in, const int* in_sizes, int n_in,
                              void* d_out, int out_size, void* d_ws, size_t ws_size,
                              hipStream_t stream) {
    const float* x  = (const float*)d_in[0];
    const float* Wq = (const float*)d_in[1];
    const float* bq = (const float*)d_in[2];
    const float* Wk = (const float*)d_in[3];
    const float* bk = (const float*)d_in[4];
    const float* Wv = (const float*)d_in[5];
    const float* bv = (const float*)d_in[6];
    const float* Wp = (const float*)d_in[7];
    const float* bp = (const float*)d_in[8];
    float* out = (float*)d_out;
    char* ws = (char*)d_ws;

    // ws layout
    float* pooled = (float*)ws;                               // 1024*64*4    = 256 KB
    float* qb     = (float*)(ws + 262144);                    // 1024*512*4   = 2 MB
    float* kb     = (float*)(ws + 262144 + 2097152);          // 2 MB
    float* Mb     = (float*)(ws + 4456448);                   // 64*128*128*4 = 4 MB
    float* betab  = (float*)(ws + 8650752);                   // 64*128*4     = 32 KB
    __hip_bfloat16* attn = (__hip_bfloat16*)(ws + 8683520);   // 8*128*65536*2 = 128 MB

    pool_kernel<<<dim3(1024), dim3(256), 0, stream>>>(x, pooled);
    qk_kernel<<<dim3(1024), dim3(256), 0, stream>>>(pooled, Wq, bq, Wk, bk, qb, kb);
    am_kernel<<<dim3(64), dim3(256), 0, stream>>>(qb, kb, Wv, bv, Mb, betab);
    attn_kernel<<<dim3(4096), dim3(256), 0, stream>>>(x, Mb, betab, attn);
    dwconv_kernel<<<dim3(16384), dim3(256), 0, stream>>>(attn, Wp, bp, out);
}

// Round 2
// 435.227 us; speedup vs baseline: 1.3629x; 1.3629x over previous
//
#include <hip/hip_runtime.h>
#include <hip/hip_bf16.h>

#define HW 65536
#define CCH 128

typedef __attribute__((ext_vector_type(8))) short short8;
typedef __attribute__((ext_vector_type(4))) float f32x4;
typedef __attribute__((ext_vector_type(8))) unsigned short u16x8;

__device__ __forceinline__ void gload_lds16(const void* g, void* l) {
    __builtin_amdgcn_global_load_lds((const __attribute__((address_space(1))) void*)g,
                                     (__attribute__((address_space(3))) void*)l, 16, 0, 0);
}
__device__ __forceinline__ unsigned short f2bf(float f) {
    union { float f; unsigned int i; } u; u.f = f;
    unsigned int r = u.i + 0x7fffu + ((u.i >> 16) & 1u);
    return (unsigned short)(r >> 16);
}
__device__ __forceinline__ float bf2f(unsigned short h) {
    union { unsigned int i; float f; } u; u.i = ((unsigned int)h) << 16; return u.f;
}

// ---------------- K1: adaptive avg pool 256x256 -> 8x8 (block means) ----------------
__global__ __launch_bounds__(256) void pool_kernel(const float* __restrict__ x,
                                                   float* __restrict__ pooled) {
    int bc = blockIdx.x;
    const float* base = x + (size_t)bc * HW;
    int t = threadIdx.x;
    for (int py = 0; py < 8; ++py) {
        float acc = 0.f;
        const float* rowp = base + py * 32 * 256 + t;
        #pragma unroll
        for (int r = 0; r < 32; ++r) acc += rowp[r * 256];
        for (int off = 16; off > 0; off >>= 1) acc += __shfl_down(acc, off, 32);
        if ((t & 31) == 0)
            pooled[(size_t)bc * 64 + py * 8 + (t >> 5)] = acc * (1.0f / 1024.0f);
    }
}

// ---------------- K2: q = relu(pooled@Wq^T+bq), k likewise ----------------
__global__ __launch_bounds__(256) void qk_kernel(const float* __restrict__ pooled,
        const float* __restrict__ Wq, const float* __restrict__ bq,
        const float* __restrict__ Wk, const float* __restrict__ bk,
        float* __restrict__ qo, float* __restrict__ ko) {
    int bc = blockIdx.x;
    int t = threadIdx.x;
    __shared__ float ps[64];
    if (t < 64) ps[t] = pooled[(size_t)bc * 64 + t];
    __syncthreads();
    for (int m = 0; m < 2; ++m) {
        const float* W = m ? Wk : Wq;
        const float* bb = m ? bk : bq;
        float* o = m ? ko : qo;
        for (int oi = t; oi < 512; oi += 256) {
            float acc = bb[oi];
            const float* wr = W + oi * 64;
            #pragma unroll
            for (int p = 0; p < 64; ++p) acc += ps[p] * wr[p];
            o[(size_t)bc * 512 + oi] = fmaxf(acc, 0.f);
        }
    }
}

// ---------------- K3: per (b,h): A=q@k^T, rownorm, M=A_n@Wv (bf16 hi/lo), beta=A_n@bv ----------------
__global__ __launch_bounds__(256) void am_kernel(const float* __restrict__ q,
        const float* __restrict__ k,
        const float* __restrict__ Wv, const float* __restrict__ bv,
        __hip_bfloat16* __restrict__ Mbf, float* __restrict__ beta) {
    int bh = blockIdx.x;
    int b = bh >> 3, h = bh & 7;
    int t = threadIdx.x;
    __shared__ float smem[128 * 128];
    float* qs = smem;
    float* ks = smem + 128 * 64;
    for (int i = t; i < 128 * 64; i += 256) {
        int c = i >> 6, p = i & 63;
        qs[c * 64 + p] = q[((size_t)(b * CCH + c)) * 512 + h * 64 + p];
        ks[c * 64 + p] = k[((size_t)(b * CCH + c)) * 512 + h * 64 + p];
    }
    __syncthreads();
    int c = t >> 1, half = t & 1;
    float a[64];
    for (int j = 0; j < 64; ++j) {
        int d = half * 64 + j;
        float acc = 0.f;
        #pragma unroll
        for (int p = 0; p < 64; ++p) acc += qs[c * 64 + p] * ks[d * 64 + p];
        a[j] = acc;
    }
    float s = 0.f;
    for (int j = 0; j < 64; ++j) s += a[j];
    s += __shfl_xor(s, 1);
    float inv = 1.0f / (s + 1e-7f);
    __syncthreads();
    float* As = smem;
    for (int j = 0; j < 64; ++j) As[c * 128 + half * 64 + j] = a[j] * inv;
    __syncthreads();
    float acc2[64];
    for (int j = 0; j < 64; ++j) acc2[j] = 0.f;
    for (int d = 0; d < 128; ++d) {
        float av = As[c * 128 + d];
        const float* wr = Wv + d * 128 + half * 64;
        #pragma unroll
        for (int j = 0; j < 64; ++j) acc2[j] += av * wr[j];
    }
    unsigned short* Mo = (unsigned short*)Mbf;
    for (int j = 0; j < 64; ++j) {
        float v = acc2[j];
        unsigned short hi = f2bf(v);
        unsigned short lo = f2bf(v - bf2f(hi));
        Mo[(size_t)bh * 32768 + c * 128 + half * 64 + j] = hi;
        Mo[(size_t)bh * 32768 + 16384 + c * 128 + half * 64 + j] = lo;
    }
    if (half == 0) {
        float bacc = 0.f;
        for (int d = 0; d < 128; ++d) bacc += As[c * 128 + d] * bv[d];
        beta[bh * 128 + c] = bacc;
    }
}

// ---------------- K4: attn[c][s] = sum_e (Mhi+Mlo)[c][e]*x[e][s] + beta[c], bf16 MFMA ----------------
__global__ __launch_bounds__(512, 4) void attn_kernel(
        const float* __restrict__ x,
        const __hip_bfloat16* __restrict__ Mbf,
        const float* __restrict__ beta,
        __hip_bfloat16* __restrict__ attn) {
    int bid = blockIdx.x;
    int b = bid >> 10;
    int h = (bid >> 7) & 7;
    int stile = bid & 127;
    int bh = b * 8 + h;
    int s0g = h * 8192 + stile * 64;
    int tid = threadIdx.x;
    int w = tid >> 6, l = tid & 63;

    __shared__ __align__(16) char sm[81920];   // Mhi@0 (32K), Mlo@32768 (32K), ts@65536 (16K)

    // ---- stage M (64 KB) linear-LDS / swizzled-source ----
    const char* Mg = (const char*)(Mbf + (size_t)bh * 32768);
    #pragma unroll
    for (int i = 0; i < 8; ++i) {
        int chunk = w * 8 + i;
        int o = chunk * 1024 + l * 16;
        int osw = o ^ (((o >> 8) & 7) << 4);
        gload_lds16(Mg + osw, sm + chunk * 1024);
    }
    // ---- stage x tile (128e x 64s) fp32 -> bf16, transposed ts[s][e], swizzled ----
    char* ts = sm + 65536;
    const float* xb = x + (size_t)b * CCH * HW + s0g;
    #pragma unroll
    for (int i = 0; i < 4; ++i) {
        int idx = i * 512 + tid;
        int e = idx >> 4;
        int s4 = (idx & 15) * 4;
        float4 v = *(const float4*)(xb + (size_t)e * HW + s4);
        float vv[4] = {v.x, v.y, v.z, v.w};
        #pragma unroll
        for (int j = 0; j < 4; ++j) {
            int s = s4 + j;
            int o = (s * 256 + e * 2) ^ ((s & 7) << 4);
            *(unsigned short*)(ts + o) = f2bf(vv[j]);
        }
    }
    __syncthreads();

    int c0w = (w >> 1) * 32;   // wave's 32-channel strip
    int s0w = (w & 1) * 32;    // wave's 32-spatial strip
    f32x4 acc[2][2] = {};
    #pragma unroll
    for (int ks = 0; ks < 4; ++ks) {
        int e0b = ks * 64;     // bytes: e0 = ks*32 elements
        short8 af[2], bhf[2], blf[2];
        #pragma unroll
        for (int si = 0; si < 2; ++si) {
            int s = s0w + si * 16 + (l & 15);
            int o = (s * 256 + e0b + ((l >> 4) * 16)) ^ ((s & 7) << 4);
            af[si] = *(const short8*)(ts + o);
        }
        #pragma unroll
        for (int ci = 0; ci < 2; ++ci) {
            int c = c0w + ci * 16 + (l & 15);
            int o = (c * 256 + e0b + ((l >> 4) * 16)) ^ ((c & 7) << 4);
            bhf[ci] = *(const short8*)(sm + o);
            blf[ci] = *(const short8*)(sm + 32768 + o);
        }
        #pragma unroll
        for (int si = 0; si < 2; ++si)
            #pragma unroll
            for (int ci = 0; ci < 2; ++ci) {
                acc[si][ci] = __builtin_amdgcn_mfma_f32_16x16x32_bf16(af[si], bhf[ci], acc[si][ci], 0, 0, 0);
                acc[si][ci] = __builtin_amdgcn_mfma_f32_16x16x32_bf16(af[si], blf[ci], acc[si][ci], 0, 0, 0);
            }
    }
    const float* bet = beta + bh * 128;
    float bv0 = bet[c0w + (l & 15)];
    float bv1 = bet[c0w + 16 + (l & 15)];
    __syncthreads();   // M region dead -> reuse sm[0:16384] as out-stage ob[c][s]
    #pragma unroll
    for (int si = 0; si < 2; ++si)
        #pragma unroll
        for (int ci = 0; ci < 2; ++ci) {
            int sb = s0w + si * 16 + (l >> 4) * 4;
            int c = c0w + ci * 16 + (l & 15);
            float bvv = ci ? bv1 : bv0;
            union { unsigned short u[4]; uint2 v; } pk;
            #pragma unroll
            for (int r = 0; r < 4; ++r) pk.u[r] = f2bf(acc[si][ci][r] + bvv);
            int o = (c * 128 + sb * 2) ^ ((c & 7) << 4);
            *(uint2*)(sm + o) = pk.v;
        }
    __syncthreads();
    char* ob = (char*)(attn + (size_t)b * CCH * HW + s0g);
    #pragma unroll
    for (int p = 0; p < 2; ++p) {
        int c = p * 64 + (tid >> 3);
        int kk = tid & 7;
        int o = (c * 128 + kk * 16) ^ ((c & 7) << 4);
        *(int4*)(ob + (size_t)c * (HW * 2) + kk * 16) = *(const int4*)(sm + o);
    }
}

// ---------------- K5: depthwise 3x3 pad1 + bp, bf16 in -> fp32 out ----------------
__global__ __launch_bounds__(256) void dwconv_kernel(const __hip_bfloat16* __restrict__ attn,
        const float* __restrict__ Wp, const float* __restrict__ bp,
        float* __restrict__ out) {
    int bid = blockIdx.x;
    int bc = bid >> 3;
    int ys = bid & 7;
    int y0 = ys * 32;
    int t = threadIdx.x;
    __shared__ unsigned short tile[34][264];
    const unsigned short* base = (const unsigned short*)attn + (size_t)bc * HW;
    for (int i = t; i < 34 * 32; i += 256) {
        int r = i >> 5, ck = i & 31;
        int gy = y0 + r - 1;
        u16x8 v;
        if (gy >= 0 && gy < 256) v = *(const u16x8*)(base + gy * 256 + ck * 8);
        else v = (u16x8)((unsigned short)0);
        *(u16x8*)&tile[r][ck * 8] = v;
    }
    __syncthreads();
    int c = bc & 127;
    float wv[9];
    #pragma unroll
    for (int j = 0; j < 9; ++j) wv[j] = Wp[c * 9 + j];
    float bias = bp[c];
    float* obase = out + (size_t)bc * HW;
    for (int p = 0; p < 4; ++p) {
        int orow = p * 8 + (t >> 5);
        int oc = (t & 31) * 8;
        float accv[8];
        #pragma unroll
        for (int j = 0; j < 8; ++j) accv[j] = bias;
        #pragma unroll
        for (int dy = 0; dy < 3; ++dy) {
            int tr = orow + dy;
            u16x8 m = *(const u16x8*)&tile[tr][oc];
            float f[10];
            f[0] = (oc == 0) ? 0.f : bf2f(tile[tr][oc - 1]);
            #pragma unroll
            for (int j = 0; j < 8; ++j) f[j + 1] = bf2f(m[j]);
            f[9] = (oc == 248) ? 0.f : bf2f(tile[tr][oc + 8]);
            float w0 = wv[dy * 3], w1 = wv[dy * 3 + 1], w2 = wv[dy * 3 + 2];
            #pragma unroll
            for (int j = 0; j < 8; ++j)
                accv[j] += w0 * f[j] + w1 * f[j + 1] + w2 * f[j + 2];
        }
        float* op = obase + (size_t)(y0 + orow) * 256 + oc;
        float4 o0 = {accv[0], accv[1], accv[2], accv[3]};
        float4 o1 = {accv[4], accv[5], accv[6], accv[7]};
        *(float4*)op = o0;
        *(float4*)(op + 4) = o1;
    }
}

extern "C" void kernel_launch(void* const* d_in, const int* in_sizes, int n_in,
                              void* d_out, int out_size, void* d_ws, size_t ws_size,
                              hipStream_t stream) {
    const float* x  = (const float*)d_in[0];
    const float* Wq = (const float*)d_in[1];
    const float* bq = (const float*)d_in[2];
    const float* Wk = (const float*)d_in[3];
    const float* bk = (const float*)d_in[4];
    const float* Wv = (const float*)d_in[5];
    const float* bv = (const float*)d_in[6];
    const float* Wp = (const float*)d_in[7];
    const float* bp = (const float*)d_in[8];
    float* out = (float*)d_out;
    char* ws = (char*)d_ws;

    float* pooled = (float*)ws;                               // 256 KB
    float* qb     = (float*)(ws + 262144);                    // 2 MB
    float* kb     = (float*)(ws + 2359296);                   // 2 MB
    __hip_bfloat16* Mbf = (__hip_bfloat16*)(ws + 4456448);    // 64*2*128*128*2B = 4 MB
    float* betab  = (float*)(ws + 8650752);                   // 32 KB
    __hip_bfloat16* attn = (__hip_bfloat16*)(ws + 8683520);   // 128 MB

    pool_kernel<<<dim3(1024), dim3(256), 0, stream>>>(x, pooled);
    qk_kernel<<<dim3(1024), dim3(256), 0, stream>>>(pooled, Wq, bq, Wk, bk, qb, kb);
    am_kernel<<<dim3(64), dim3(256), 0, stream>>>(qb, kb, Wv, bv, Mbf, betab);
    attn_kernel<<<dim3(8192), dim3(512), 0, stream>>>(x, Mbf, betab, attn);
    dwconv_kernel<<<dim3(8192), dim3(256), 0, stream>>>(attn, Wp, bp, out);
}

// Round 3
// 411.069 us; speedup vs baseline: 1.4429x; 1.0588x over previous
//
#include <hip/hip_runtime.h>
#include <hip/hip_bf16.h>

#define HW 65536
#define CCH 128

typedef __attribute__((ext_vector_type(8))) short short8;
typedef __attribute__((ext_vector_type(4))) float f32x4;
typedef __attribute__((ext_vector_type(8))) unsigned short u16x8;

__device__ __forceinline__ void gload_lds16(const void* g, void* l) {
    __builtin_amdgcn_global_load_lds((const __attribute__((address_space(1))) void*)g,
                                     (__attribute__((address_space(3))) void*)l, 16, 0, 0);
}
__device__ __forceinline__ unsigned short f2bf(float f) {
    union { float f; unsigned int i; } u; u.f = f;
    unsigned int r = u.i + 0x7fffu + ((u.i >> 16) & 1u);
    return (unsigned short)(r >> 16);
}
__device__ __forceinline__ float bf2f(unsigned short h) {
    union { unsigned int i; float f; } u; u.i = ((unsigned int)h) << 16; return u.f;
}

// ---------------- K1: adaptive avg pool 256x256 -> 8x8 (block means) ----------------
__global__ __launch_bounds__(256) void pool_kernel(const float* __restrict__ x,
                                                   float* __restrict__ pooled) {
    int bc = blockIdx.x;
    const float* base = x + (size_t)bc * HW;
    int t = threadIdx.x;
    for (int py = 0; py < 8; ++py) {
        float acc = 0.f;
        const float* rowp = base + py * 32 * 256 + t;
        #pragma unroll
        for (int r = 0; r < 32; ++r) acc += rowp[r * 256];
        for (int off = 16; off > 0; off >>= 1) acc += __shfl_down(acc, off, 32);
        if ((t & 31) == 0)
            pooled[(size_t)bc * 64 + py * 8 + (t >> 5)] = acc * (1.0f / 1024.0f);
    }
}

// ---------------- K2: q = relu(pooled@Wq^T+bq), k likewise ----------------
__global__ __launch_bounds__(256) void qk_kernel(const float* __restrict__ pooled,
        const float* __restrict__ Wq, const float* __restrict__ bq,
        const float* __restrict__ Wk, const float* __restrict__ bk,
        float* __restrict__ qo, float* __restrict__ ko) {
    int bc = blockIdx.x;
    int t = threadIdx.x;
    __shared__ float ps[64];
    if (t < 64) ps[t] = pooled[(size_t)bc * 64 + t];
    __syncthreads();
    for (int m = 0; m < 2; ++m) {
        const float* W = m ? Wk : Wq;
        const float* bb = m ? bk : bq;
        float* o = m ? ko : qo;
        for (int oi = t; oi < 512; oi += 256) {
            float acc = bb[oi];
            const float* wr = W + oi * 64;
            #pragma unroll
            for (int p = 0; p < 64; ++p) acc += ps[p] * wr[p];
            o[(size_t)bc * 512 + oi] = fmaxf(acc, 0.f);
        }
    }
}

// ---------------- K3: per (b,h): A=q@k^T, rownorm, M=A_n@Wv (bf16), beta=A_n@bv ----------------
__global__ __launch_bounds__(256) void am_kernel(const float* __restrict__ q,
        const float* __restrict__ k,
        const float* __restrict__ Wv, const float* __restrict__ bv,
        __hip_bfloat16* __restrict__ Mbf, float* __restrict__ beta) {
    int bh = blockIdx.x;
    int b = bh >> 3, h = bh & 7;
    int t = threadIdx.x;
    __shared__ float smem[128 * 128];
    float* qs = smem;
    float* ks = smem + 128 * 64;
    for (int i = t; i < 128 * 64; i += 256) {
        int c = i >> 6, p = i & 63;
        qs[c * 64 + p] = q[((size_t)(b * CCH + c)) * 512 + h * 64 + p];
        ks[c * 64 + p] = k[((size_t)(b * CCH + c)) * 512 + h * 64 + p];
    }
    __syncthreads();
    int c = t >> 1, half = t & 1;
    float a[64];
    for (int j = 0; j < 64; ++j) {
        int d = half * 64 + j;
        float acc = 0.f;
        #pragma unroll
        for (int p = 0; p < 64; ++p) acc += qs[c * 64 + p] * ks[d * 64 + p];
        a[j] = acc;
    }
    float s = 0.f;
    for (int j = 0; j < 64; ++j) s += a[j];
    s += __shfl_xor(s, 1);
    float inv = 1.0f / (s + 1e-7f);
    __syncthreads();
    float* As = smem;
    for (int j = 0; j < 64; ++j) As[c * 128 + half * 64 + j] = a[j] * inv;
    __syncthreads();
    float acc2[64];
    for (int j = 0; j < 64; ++j) acc2[j] = 0.f;
    for (int d = 0; d < 128; ++d) {
        float av = As[c * 128 + d];
        const float* wr = Wv + d * 128 + half * 64;
        #pragma unroll
        for (int j = 0; j < 64; ++j) acc2[j] += av * wr[j];
    }
    unsigned short* Mo = (unsigned short*)Mbf;
    for (int j = 0; j < 64; ++j)
        Mo[(size_t)bh * 16384 + c * 128 + half * 64 + j] = f2bf(acc2[j]);
    if (half == 0) {
        float bacc = 0.f;
        for (int d = 0; d < 128; ++d) bacc += As[c * 128 + d] * bv[d];
        beta[bh * 128 + c] = bacc;
    }
}

// ---------------- K4: attn[c][s] = sum_e M[c][e]*x[e][s] + beta[c], bf16 MFMA ----------------
// grid: 64 bh * 16 chunks; each block: stage M once, loop 8 double-buffered 64-s tiles
__global__ __launch_bounds__(512, 4) void attn_kernel(
        const float* __restrict__ x,
        const __hip_bfloat16* __restrict__ Mbf,
        const float* __restrict__ beta,
        __hip_bfloat16* __restrict__ attn) {
    int bid = blockIdx.x;
    int bh = bid >> 4;
    int chunk = bid & 15;
    int b = bh >> 3, h = bh & 7;
    int s0g = h * 8192 + chunk * 512;
    int tid = threadIdx.x;
    int w = tid >> 6, l = tid & 63;

    __shared__ __align__(16) char sm[65536];  // M@0 (32K, becomes outstage), ts dbuf @32768 (2x16K)
    char* ts0 = sm + 32768;

    // ---- stage M (32 KB) linear-LDS / swizzled-source ----
    const char* Mg = (const char*)(Mbf + (size_t)bh * 16384);
    #pragma unroll
    for (int i = 0; i < 4; ++i) {
        int o = i * 8192 + tid * 16;
        int osw = o ^ (((o >> 8) & 7) << 4);
        gload_lds16(Mg + osw, sm + o);
    }

    // staging decomposition: thread covers e rows {e0u, e0u+1, e0u+64, e0u+65} at s-quad s4u
    int e0u = (tid >> 4) * 2;
    int s4u = (tid & 15) * 4;
    const float* xb = x + (size_t)b * CCH * HW + s0g;

    f32x4 rg[4];
    #define LOADT(t_) do { \
        const float* p0 = xb + (size_t)e0u * HW + (t_) * 64 + s4u; \
        rg[0] = *(const f32x4*)p0; \
        rg[1] = *(const f32x4*)(p0 + HW); \
        const float* p1 = p0 + (size_t)64 * HW; \
        rg[2] = *(const f32x4*)p1; \
        rg[3] = *(const f32x4*)(p1 + HW); \
    } while (0)
    #define WRITET(buf_) do { \
        _Pragma("unroll") \
        for (int j = 0; j < 4; ++j) { \
            int s = s4u + j; \
            int sw = (s & 7) << 4; \
            unsigned int pa = (unsigned int)f2bf(rg[0][j]) | ((unsigned int)f2bf(rg[1][j]) << 16); \
            unsigned int pb = (unsigned int)f2bf(rg[2][j]) | ((unsigned int)f2bf(rg[3][j]) << 16); \
            *(unsigned int*)((buf_) + ((s * 256 + e0u * 2) ^ sw)) = pa; \
            *(unsigned int*)((buf_) + ((s * 256 + (e0u + 64) * 2) ^ sw)) = pb; \
        } \
    } while (0)

    LOADT(0);
    WRITET(ts0);
    __syncthreads();   // M + tile0 staged

    // hoist loop-invariant M fragments (B operand) into registers
    int c0w = (w >> 1) * 32;
    int s0w = (w & 1) * 32;
    short8 mf[2][4];
    #pragma unroll
    for (int ci = 0; ci < 2; ++ci)
        #pragma unroll
        for (int ks = 0; ks < 4; ++ks) {
            int c = c0w + ci * 16 + (l & 15);
            int o = (c * 256 + ks * 64 + ((l >> 4) * 16)) ^ ((c & 7) << 4);
            mf[ci][ks] = *(const short8*)(sm + o);
        }
    const float* bet = beta + bh * 128;
    float bv0 = bet[c0w + (l & 15)];
    float bv1 = bet[c0w + 16 + (l & 15)];

    for (int t = 0; t < 8; ++t) {
        char* tsc = ts0 + (t & 1) * 16384;
        char* tsn = ts0 + ((t + 1) & 1) * 16384;
        if (t < 7) LOADT(t + 1);          // issue next-tile global loads early
        f32x4 acc[2][2] = {};
        #pragma unroll
        for (int ks = 0; ks < 4; ++ks) {
            short8 af[2];
            #pragma unroll
            for (int si = 0; si < 2; ++si) {
                int s = s0w + si * 16 + (l & 15);
                int o = (s * 256 + ks * 64 + ((l >> 4) * 16)) ^ ((s & 7) << 4);
                af[si] = *(const short8*)(tsc + o);
            }
            #pragma unroll
            for (int si = 0; si < 2; ++si)
                #pragma unroll
                for (int ci = 0; ci < 2; ++ci)
                    acc[si][ci] = __builtin_amdgcn_mfma_f32_16x16x32_bf16(af[si], mf[ci][ks], acc[si][ci], 0, 0, 0);
        }
        __syncthreads();                   // A: tsc reads done, outstage free
        if (t < 7) WRITET(tsn);
        #pragma unroll
        for (int si = 0; si < 2; ++si)
            #pragma unroll
            for (int ci = 0; ci < 2; ++ci) {
                int sb = s0w + si * 16 + (l >> 4) * 4;
                int c = c0w + ci * 16 + (l & 15);
                float bvv = ci ? bv1 : bv0;
                union { unsigned short u[4]; uint2 v; } pk;
                #pragma unroll
                for (int r = 0; r < 4; ++r) pk.u[r] = f2bf(acc[si][ci][r] + bvv);
                int o = (c * 128 + sb * 2) ^ ((c & 7) << 4);
                *(uint2*)(sm + o) = pk.v;
            }
        __syncthreads();                   // B: outstage + next ts ready
        char* ob = (char*)attn + ((size_t)b * CCH * HW + s0g + t * 64) * 2;
        #pragma unroll
        for (int p = 0; p < 2; ++p) {
            int c = p * 64 + (tid >> 3);
            int kk = tid & 7;
            int o = (c * 128 + kk * 16) ^ ((c & 7) << 4);
            *(int4*)(ob + (size_t)c * (HW * 2) + kk * 16) = *(const int4*)(sm + o);
        }
    }
    #undef LOADT
    #undef WRITET
}

// ---------------- K5: depthwise 3x3 pad1 + bp, bf16 in -> fp32 out ----------------
__global__ __launch_bounds__(256) void dwconv_kernel(const __hip_bfloat16* __restrict__ attn,
        const float* __restrict__ Wp, const float* __restrict__ bp,
        float* __restrict__ out) {
    int bid = blockIdx.x;
    int bc = bid >> 3;
    int ys = bid & 7;
    int y0 = ys * 32;
    int t = threadIdx.x;
    __shared__ unsigned short tile[34][264];
    const unsigned short* base = (const unsigned short*)attn + (size_t)bc * HW;
    for (int i = t; i < 34 * 32; i += 256) {
        int r = i >> 5, ck = i & 31;
        int gy = y0 + r - 1;
        u16x8 v;
        if (gy >= 0 && gy < 256) v = *(const u16x8*)(base + gy * 256 + ck * 8);
        else v = (u16x8)((unsigned short)0);
        *(u16x8*)&tile[r][ck * 8] = v;
    }
    __syncthreads();
    int c = bc & 127;
    float wv[9];
    #pragma unroll
    for (int j = 0; j < 9; ++j) wv[j] = Wp[c * 9 + j];
    float bias = bp[c];
    float* obase = out + (size_t)bc * HW;
    for (int p = 0; p < 4; ++p) {
        int orow = p * 8 + (t >> 5);
        int oc = (t & 31) * 8;
        float accv[8];
        #pragma unroll
        for (int j = 0; j < 8; ++j) accv[j] = bias;
        #pragma unroll
        for (int dy = 0; dy < 3; ++dy) {
            int tr = orow + dy;
            u16x8 m = *(const u16x8*)&tile[tr][oc];
            float f[10];
            f[0] = (oc == 0) ? 0.f : bf2f(tile[tr][oc - 1]);
            #pragma unroll
            for (int j = 0; j < 8; ++j) f[j + 1] = bf2f(m[j]);
            f[9] = (oc == 248) ? 0.f : bf2f(tile[tr][oc + 8]);
            float w0 = wv[dy * 3], w1 = wv[dy * 3 + 1], w2 = wv[dy * 3 + 2];
            #pragma unroll
            for (int j = 0; j < 8; ++j)
                accv[j] += w0 * f[j] + w1 * f[j + 1] + w2 * f[j + 2];
        }
        float* op = obase + (size_t)(y0 + orow) * 256 + oc;
        float4 o0 = {accv[0], accv[1], accv[2], accv[3]};
        float4 o1 = {accv[4], accv[5], accv[6], accv[7]};
        *(float4*)op = o0;
        *(float4*)(op + 4) = o1;
    }
}

extern "C" void kernel_launch(void* const* d_in, const int* in_sizes, int n_in,
                              void* d_out, int out_size, void* d_ws, size_t ws_size,
                              hipStream_t stream) {
    const float* x  = (const float*)d_in[0];
    const float* Wq = (const float*)d_in[1];
    const float* bq = (const float*)d_in[2];
    const float* Wk = (const float*)d_in[3];
    const float* bk = (const float*)d_in[4];
    const float* Wv = (const float*)d_in[5];
    const float* bv = (const float*)d_in[6];
    const float* Wp = (const float*)d_in[7];
    const float* bp = (const float*)d_in[8];
    float* out = (float*)d_out;
    char* ws = (char*)d_ws;

    float* pooled = (float*)ws;                               // 256 KB
    float* qb     = (float*)(ws + 262144);                    // 2 MB
    float* kb     = (float*)(ws + 2359296);                   // 2 MB
    __hip_bfloat16* Mbf = (__hip_bfloat16*)(ws + 4456448);    // 64*128*128*2B = 2 MB
    float* betab  = (float*)(ws + 6553600);                   // 32 KB
    __hip_bfloat16* attn = (__hip_bfloat16*)(ws + 6586368);   // 128 MB

    pool_kernel<<<dim3(1024), dim3(256), 0, stream>>>(x, pooled);
    qk_kernel<<<dim3(1024), dim3(256), 0, stream>>>(pooled, Wq, bq, Wk, bk, qb, kb);
    am_kernel<<<dim3(64), dim3(256), 0, stream>>>(qb, kb, Wv, bv, Mbf, betab);
    attn_kernel<<<dim3(1024), dim3(512), 0, stream>>>(x, Mbf, betab, attn);
    dwconv_kernel<<<dim3(8192), dim3(256), 0, stream>>>(attn, Wp, bp, out);
}

// Round 4
// 306.474 us; speedup vs baseline: 1.9354x; 1.3413x over previous
//
#include <hip/hip_runtime.h>
#include <hip/hip_bf16.h>

#define HW 65536
#define CCH 128

typedef __attribute__((ext_vector_type(8))) short short8;
typedef __attribute__((ext_vector_type(4))) float f32x4;
typedef __attribute__((ext_vector_type(8))) unsigned short u16x8;

__device__ __forceinline__ void gload_lds16(const void* g, void* l) {
    __builtin_amdgcn_global_load_lds((const __attribute__((address_space(1))) void*)g,
                                     (__attribute__((address_space(3))) void*)l, 16, 0, 0);
}
__device__ __forceinline__ unsigned short f2bf(float f) {
    union { float f; unsigned int i; } u; u.f = f;
    unsigned int r = u.i + 0x7fffu + ((u.i >> 16) & 1u);
    return (unsigned short)(r >> 16);
}
__device__ __forceinline__ float bf2f(unsigned short h) {
    union { unsigned int i; float f; } u; u.i = ((unsigned int)h) << 16; return u.f;
}

// ---------------- K1: adaptive avg pool 256x256 -> 8x8 (block means) ----------------
__global__ __launch_bounds__(256) void pool_kernel(const float* __restrict__ x,
                                                   float* __restrict__ pooled) {
    int bc = blockIdx.x;
    const float* base = x + (size_t)bc * HW;
    int t = threadIdx.x;
    for (int py = 0; py < 8; ++py) {
        float acc = 0.f;
        const float* rowp = base + py * 32 * 256 + t;
        #pragma unroll
        for (int r = 0; r < 32; ++r) acc += rowp[r * 256];
        for (int off = 16; off > 0; off >>= 1) acc += __shfl_down(acc, off, 32);
        if ((t & 31) == 0)
            pooled[(size_t)bc * 64 + py * 8 + (t >> 5)] = acc * (1.0f / 1024.0f);
    }
}

// ---------------- K2: q = relu(pooled@Wq^T+bq), k likewise ----------------
__global__ __launch_bounds__(256) void qk_kernel(const float* __restrict__ pooled,
        const float* __restrict__ Wq, const float* __restrict__ bq,
        const float* __restrict__ Wk, const float* __restrict__ bk,
        float* __restrict__ qo, float* __restrict__ ko) {
    int bc = blockIdx.x;
    int t = threadIdx.x;
    __shared__ float ps[64];
    if (t < 64) ps[t] = pooled[(size_t)bc * 64 + t];
    __syncthreads();
    for (int m = 0; m < 2; ++m) {
        const float* W = m ? Wk : Wq;
        const float* bb = m ? bk : bq;
        float* o = m ? ko : qo;
        for (int oi = t; oi < 512; oi += 256) {
            float acc = bb[oi];
            const float* wr = W + oi * 64;
            #pragma unroll
            for (int p = 0; p < 64; ++p) acc += ps[p] * wr[p];
            o[(size_t)bc * 512 + oi] = fmaxf(acc, 0.f);
        }
    }
}

// ---------------- K3a: per (b,h): A=q@k^T rows, rownorm, beta; A_n out as bf16 hi+lo ----------------
// grid: 64 bh * 4 c-groups of 32 rows; 256 threads = 32 rows x 8 d-chunks of 16
__global__ __launch_bounds__(256) void am1_kernel(const float* __restrict__ q,
        const float* __restrict__ k, const float* __restrict__ bv,
        unsigned short* __restrict__ Ahi, unsigned short* __restrict__ Alo,
        float* __restrict__ beta) {
    int bid = blockIdx.x;
    int bh = bid >> 2;
    int cg = bid & 3;
    int b = bh >> 3, h = bh & 7;
    int t = threadIdx.x;
    __shared__ float ks[128 * 68];   // padded stride 68 -> conflict-free b128
    __shared__ float qs[32 * 68];
    __shared__ float bvs[128];
    for (int i = t; i < 2048; i += 256) {       // k: 128 rows x 16 f32x4
        int d = i >> 4, p4 = (i & 15) * 4;
        *(f32x4*)&ks[d * 68 + p4] = *(const f32x4*)(k + ((size_t)(b * CCH + d)) * 512 + h * 64 + p4);
    }
    for (int i = t; i < 512; i += 256) {        // q: 32 rows x 16 f32x4
        int cl = i >> 4, p4 = (i & 15) * 4;
        *(f32x4*)&qs[cl * 68 + p4] = *(const f32x4*)(q + ((size_t)(b * CCH + cg * 32 + cl)) * 512 + h * 64 + p4);
    }
    if (t < 128) bvs[t] = bv[t];
    __syncthreads();
    int cl = t >> 3, dc = t & 7;
    int c = cg * 32 + cl;
    int d0 = dc * 16;
    f32x4 qr[16];
    #pragma unroll
    for (int ch = 0; ch < 16; ++ch) qr[ch] = *(const f32x4*)&qs[cl * 68 + ch * 4];
    float a[16];
    #pragma unroll
    for (int j = 0; j < 16; ++j) {
        int d = d0 + j;
        float acc = 0.f;
        #pragma unroll
        for (int ch = 0; ch < 16; ++ch) {
            f32x4 kr = *(const f32x4*)&ks[d * 68 + ch * 4];
            acc += qr[ch].x * kr.x + qr[ch].y * kr.y + qr[ch].z * kr.z + qr[ch].w * kr.w;
        }
        a[j] = acc;
    }
    float s = 0.f;
    #pragma unroll
    for (int j = 0; j < 16; ++j) s += a[j];
    s += __shfl_xor(s, 1);
    s += __shfl_xor(s, 2);
    s += __shfl_xor(s, 4);
    float inv = 1.0f / (s + 1e-7f);
    float bpart = 0.f;
    union { unsigned short u[16]; uint4 v[2]; } ph, pl;
    #pragma unroll
    for (int j = 0; j < 16; ++j) {
        float an = a[j] * inv;
        bpart += an * bvs[d0 + j];
        unsigned short hi = f2bf(an);
        ph.u[j] = hi;
        pl.u[j] = f2bf(an - bf2f(hi));
    }
    bpart += __shfl_xor(bpart, 1);
    bpart += __shfl_xor(bpart, 2);
    bpart += __shfl_xor(bpart, 4);
    if (dc == 0) beta[bh * 128 + c] = bpart;
    size_t ao = (size_t)bh * 16384 + c * 128 + d0;
    *(uint4*)(Ahi + ao) = ph.v[0];
    *(uint4*)(Ahi + ao + 8) = ph.v[1];
    *(uint4*)(Alo + ao) = pl.v[0];
    *(uint4*)(Alo + ao + 8) = pl.v[1];
}

// ---------------- K3b: WvT bf16 hi/lo (transpose) ----------------
__global__ __launch_bounds__(256) void wvt_kernel(const float* __restrict__ Wv,
        unsigned short* __restrict__ WvThi, unsigned short* __restrict__ WvTlo) {
    int idx = blockIdx.x * 256 + threadIdx.x;   // 16384 total
    int d = idx >> 7, e = idx & 127;
    float v = Wv[d * 128 + e];
    unsigned short hi = f2bf(v);
    WvThi[e * 128 + d] = hi;
    WvTlo[e * 128 + d] = f2bf(v - bf2f(hi));
}

// ---------------- K3c: M = A_n @ Wv via MFMA (hi/lo x hi/lo, drop lo*lo) ----------------
// grid: 64 bh * 2 e-halves; 256 threads = 4 waves, wave = 32c x 64e
__global__ __launch_bounds__(256) void am2_kernel(
        const unsigned short* __restrict__ Ahi, const unsigned short* __restrict__ Alo,
        const unsigned short* __restrict__ WvThi, const unsigned short* __restrict__ WvTlo,
        unsigned short* __restrict__ Mo) {
    int bid = blockIdx.x;
    int bh = bid >> 1;
    int eg = bid & 1;
    int tid = threadIdx.x;
    int w = tid >> 6, l = tid & 63;
    int lc = l & 15, lk = (l >> 4) * 8;
    f32x4 acc[2][4] = {};
    const unsigned short* Ab = Ahi + (size_t)bh * 16384;
    const unsigned short* Alb = Alo + (size_t)bh * 16384;
    #pragma unroll
    for (int ksi = 0; ksi < 4; ++ksi) {
        int d = ksi * 32 + lk;
        short8 ah[2], al[2], bhv[4], blv[4];
        #pragma unroll
        for (int ci = 0; ci < 2; ++ci) {
            int c = w * 32 + ci * 16 + lc;
            ah[ci] = *(const short8*)(Ab + c * 128 + d);
            al[ci] = *(const short8*)(Alb + c * 128 + d);
        }
        #pragma unroll
        for (int ei = 0; ei < 4; ++ei) {
            int e = eg * 64 + ei * 16 + lc;
            bhv[ei] = *(const short8*)(WvThi + e * 128 + d);
            blv[ei] = *(const short8*)(WvTlo + e * 128 + d);
        }
        #pragma unroll
        for (int ci = 0; ci < 2; ++ci)
            #pragma unroll
            for (int ei = 0; ei < 4; ++ei) {
                acc[ci][ei] = __builtin_amdgcn_mfma_f32_16x16x32_bf16(ah[ci], bhv[ei], acc[ci][ei], 0, 0, 0);
                acc[ci][ei] = __builtin_amdgcn_mfma_f32_16x16x32_bf16(ah[ci], blv[ei], acc[ci][ei], 0, 0, 0);
                acc[ci][ei] = __builtin_amdgcn_mfma_f32_16x16x32_bf16(al[ci], bhv[ei], acc[ci][ei], 0, 0, 0);
            }
    }
    unsigned short* Mb = Mo + (size_t)bh * 16384;
    #pragma unroll
    for (int ci = 0; ci < 2; ++ci)
        #pragma unroll
        for (int ei = 0; ei < 4; ++ei)
            #pragma unroll
            for (int r = 0; r < 4; ++r) {
                int c = w * 32 + ci * 16 + (l >> 4) * 4 + r;
                int e = eg * 64 + ei * 16 + lc;
                Mb[c * 128 + e] = f2bf(acc[ci][ei][r]);
            }
}

// ---------------- K4: attn[c][s] = sum_e M[c][e]*x[e][s] + beta[c], bf16 MFMA ----------------
// grid: 64 bh * 16 chunks; block: stage M once, 8 double-buffered 64-s tiles, 1 barrier/tile
__global__ __launch_bounds__(512, 4) void attn_kernel(
        const float* __restrict__ x,
        const __hip_bfloat16* __restrict__ Mbf,
        const float* __restrict__ beta,
        __hip_bfloat16* __restrict__ attn) {
    int bid = blockIdx.x;
    int bh = bid >> 4;
    int chunk = bid & 15;
    int b = bh >> 3, h = bh & 7;
    int s0g = h * 8192 + chunk * 512;
    int tid = threadIdx.x;
    int w = tid >> 6, l = tid & 63;

    __shared__ __align__(16) char sm[65536];  // M@0 (32K), ts dbuf @32768 (2x16K)
    char* ts0 = sm + 32768;

    // stage M (32 KB) linear-LDS / swizzled-source
    const char* Mg = (const char*)(Mbf + (size_t)bh * 16384);
    #pragma unroll
    for (int i = 0; i < 4; ++i) {
        int o = i * 8192 + tid * 16;
        int osw = o ^ (((o >> 8) & 7) << 4);
        gload_lds16(Mg + osw, sm + o);
    }

    int e0u = (tid >> 4) * 2;
    int s4u = (tid & 15) * 4;
    const float* xb = x + (size_t)b * CCH * HW + s0g;

    f32x4 rg[4];
    #define LOADT(t_) do { \
        const float* p0 = xb + (size_t)e0u * HW + (t_) * 64 + s4u; \
        rg[0] = *(const f32x4*)p0; \
        rg[1] = *(const f32x4*)(p0 + HW); \
        const float* p1 = p0 + (size_t)64 * HW; \
        rg[2] = *(const f32x4*)p1; \
        rg[3] = *(const f32x4*)(p1 + HW); \
    } while (0)
    #define WRITET(buf_) do { \
        _Pragma("unroll") \
        for (int j = 0; j < 4; ++j) { \
            int s = s4u + j; \
            int sw = (s & 7) << 4; \
            unsigned int pa = (unsigned int)f2bf(rg[0][j]) | ((unsigned int)f2bf(rg[1][j]) << 16); \
            unsigned int pb = (unsigned int)f2bf(rg[2][j]) | ((unsigned int)f2bf(rg[3][j]) << 16); \
            *(unsigned int*)((buf_) + ((s * 256 + e0u * 2) ^ sw)) = pa; \
            *(unsigned int*)((buf_) + ((s * 256 + (e0u + 64) * 2) ^ sw)) = pb; \
        } \
    } while (0)

    LOADT(0);
    WRITET(ts0);
    LOADT(1);
    __syncthreads();   // M + tile0 staged (drains gload_lds + LOADT(1))

    // hoist loop-invariant M fragments (B operand)
    int c0w = (w >> 1) * 32;
    int s0w = (w & 1) * 32;
    short8 mf[2][4];
    #pragma unroll
    for (int ci = 0; ci < 2; ++ci)
        #pragma unroll
        for (int ksi = 0; ksi < 4; ++ksi) {
            int c = c0w + ci * 16 + (l & 15);
            int o = (c * 256 + ksi * 64 + ((l >> 4) * 16)) ^ ((c & 7) << 4);
            mf[ci][ksi] = *(const short8*)(sm + o);
        }
    const float* bet = beta + bh * 128;
    float bv0 = bet[c0w + (l & 15)];
    float bv1 = bet[c0w + 16 + (l & 15)];
    __hip_bfloat16* ab = attn + (size_t)b * CCH * HW + s0g;

    for (int t = 0; t < 8; ++t) {
        char* tsc = ts0 + (t & 1) * 16384;
        if (t < 7) WRITET(ts0 + ((t + 1) & 1) * 16384);  // rg holds tile t+1 (prev iter load)
        if (t < 6) LOADT(t + 2);                          // issue loads for tile t+2
        f32x4 acc[2][2] = {};
        #pragma unroll
        for (int ksi = 0; ksi < 4; ++ksi) {
            short8 af[2];
            #pragma unroll
            for (int si = 0; si < 2; ++si) {
                int s = s0w + si * 16 + (l & 15);
                int o = (s * 256 + ksi * 64 + ((l >> 4) * 16)) ^ ((s & 7) << 4);
                af[si] = *(const short8*)(tsc + o);
            }
            #pragma unroll
            for (int si = 0; si < 2; ++si)
                #pragma unroll
                for (int ci = 0; ci < 2; ++ci)
                    acc[si][ci] = __builtin_amdgcn_mfma_f32_16x16x32_bf16(af[si], mf[ci][ksi], acc[si][ci], 0, 0, 0);
        }
        // direct global stores from accumulators (4 consecutive s per lane = 8B)
        #pragma unroll
        for (int si = 0; si < 2; ++si)
            #pragma unroll
            for (int ci = 0; ci < 2; ++ci) {
                int sb = s0w + si * 16 + (l >> 4) * 4;
                int c = c0w + ci * 16 + (l & 15);
                float bvv = ci ? bv1 : bv0;
                union { unsigned short u[4]; uint2 v; } pk;
                #pragma unroll
                for (int r = 0; r < 4; ++r) pk.u[r] = f2bf(acc[si][ci][r] + bvv);
                *(uint2*)(ab + (size_t)c * HW + t * 64 + sb) = pk.v;
            }
        __syncthreads();   // tsc reads done + next buf written -> safe for next iter
    }
    #undef LOADT
    #undef WRITET
}

// ---------------- K5: depthwise 3x3 pad1 + bp, bf16 in -> fp32 out ----------------
__global__ __launch_bounds__(256) void dwconv_kernel(const __hip_bfloat16* __restrict__ attn,
        const float* __restrict__ Wp, const float* __restrict__ bp,
        float* __restrict__ out) {
    int bid = blockIdx.x;
    int bc = bid >> 3;
    int ys = bid & 7;
    int y0 = ys * 32;
    int t = threadIdx.x;
    __shared__ unsigned short tile[34][264];
    const unsigned short* base = (const unsigned short*)attn + (size_t)bc * HW;
    for (int i = t; i < 34 * 32; i += 256) {
        int r = i >> 5, ck = i & 31;
        int gy = y0 + r - 1;
        u16x8 v;
        if (gy >= 0 && gy < 256) v = *(const u16x8*)(base + gy * 256 + ck * 8);
        else v = (u16x8)((unsigned short)0);
        *(u16x8*)&tile[r][ck * 8] = v;
    }
    __syncthreads();
    int c = bc & 127;
    float wv[9];
    #pragma unroll
    for (int j = 0; j < 9; ++j) wv[j] = Wp[c * 9 + j];
    float bias = bp[c];
    float* obase = out + (size_t)bc * HW;
    for (int p = 0; p < 4; ++p) {
        int orow = p * 8 + (t >> 5);
        int oc = (t & 31) * 8;
        float accv[8];
        #pragma unroll
        for (int j = 0; j < 8; ++j) accv[j] = bias;
        #pragma unroll
        for (int dy = 0; dy < 3; ++dy) {
            int tr = orow + dy;
            u16x8 m = *(const u16x8*)&tile[tr][oc];
            float f[10];
            f[0] = (oc == 0) ? 0.f : bf2f(tile[tr][oc - 1]);
            #pragma unroll
            for (int j = 0; j < 8; ++j) f[j + 1] = bf2f(m[j]);
            f[9] = (oc == 248) ? 0.f : bf2f(tile[tr][oc + 8]);
            float w0 = wv[dy * 3], w1 = wv[dy * 3 + 1], w2 = wv[dy * 3 + 2];
            #pragma unroll
            for (int j = 0; j < 8; ++j)
                accv[j] += w0 * f[j] + w1 * f[j + 1] + w2 * f[j + 2];
        }
        float* op = obase + (size_t)(y0 + orow) * 256 + oc;
        float4 o0 = {accv[0], accv[1], accv[2], accv[3]};
        float4 o1 = {accv[4], accv[5], accv[6], accv[7]};
        *(float4*)op = o0;
        *(float4*)(op + 4) = o1;
    }
}

extern "C" void kernel_launch(void* const* d_in, const int* in_sizes, int n_in,
                              void* d_out, int out_size, void* d_ws, size_t ws_size,
                              hipStream_t stream) {
    const float* x  = (const float*)d_in[0];
    const float* Wq = (const float*)d_in[1];
    const float* bq = (const float*)d_in[2];
    const float* Wk = (const float*)d_in[3];
    const float* bk = (const float*)d_in[4];
    const float* Wv = (const float*)d_in[5];
    const float* bv = (const float*)d_in[6];
    const float* Wp = (const float*)d_in[7];
    const float* bp = (const float*)d_in[8];
    float* out = (float*)d_out;
    char* ws = (char*)d_ws;

    float* pooled = (float*)ws;                               // 256 KB
    float* qb     = (float*)(ws + 262144);                    // 2 MB
    float* kb     = (float*)(ws + 2359296);                   // 2 MB
    __hip_bfloat16* Mbf = (__hip_bfloat16*)(ws + 4456448);    // 2 MB
    float* betab  = (float*)(ws + 6553600);                   // 32 KB
    char* attnp   = ws + 6586368;                             // 128 MB
    // A/WvT scratch overlaid on the attn region (dead before attn_kernel writes it)
    unsigned short* Ahi   = (unsigned short*)attnp;           // 2 MB
    unsigned short* Alo   = (unsigned short*)(attnp + 2097152);
    unsigned short* WvThi = (unsigned short*)(attnp + 4194304);
    unsigned short* WvTlo = (unsigned short*)(attnp + 4227072);

    pool_kernel<<<dim3(1024), dim3(256), 0, stream>>>(x, pooled);
    qk_kernel<<<dim3(1024), dim3(256), 0, stream>>>(pooled, Wq, bq, Wk, bk, qb, kb);
    am1_kernel<<<dim3(256), dim3(256), 0, stream>>>(qb, kb, bv, Ahi, Alo, betab);
    wvt_kernel<<<dim3(64), dim3(256), 0, stream>>>(Wv, WvThi, WvTlo);
    am2_kernel<<<dim3(128), dim3(256), 0, stream>>>(Ahi, Alo, WvThi, WvTlo, (unsigned short*)Mbf);
    attn_kernel<<<dim3(1024), dim3(512), 0, stream>>>(x, Mbf, betab, (__hip_bfloat16*)attnp);
    dwconv_kernel<<<dim3(8192), dim3(256), 0, stream>>>((const __hip_bfloat16*)attnp, Wp, bp, out);
}